// Round 3
// baseline (366.338 us; speedup 1.0000x reference)
//
#include <hip/hip_runtime.h>

#define HP 1.57079632679489662f

// ws layout:
//   int   meta[64]        @ 0    : meta[0]=n_edges, meta[1+2e],meta[2+2e]=(i,j)
//   float Ut[256][512]    @ 4096 : Ut[c][2r] = Re U[r][c], Ut[c][2r+1] = Im U[r][c]

// ---------------- K0: edge thresholding, exact numpy f64 semantics ----------------
__global__ void prep_kernel(const float* __restrict__ coup, void* __restrict__ wsv) {
  if (threadIdx.x != 0) return;
  int* meta = (int*)wsv;
  double mn = 1e300, mx = -1e300;
  for (int k = 0; k < 64; k++) {
    double v = (double)coup[k];
    mn = v < mn ? v : mn;
    mx = v > mx ? v : mx;
  }
  int cnt = 0;
  for (int i = 0; i < 8; i++)
    for (int j = i + 1; j < 8; j++) {
      double cn = ((double)coup[i * 8 + j] - mn) / (mx - mn);
      if (cn > 0.5) {
        meta[1 + 2 * cnt] = i;
        meta[2 + 2 * cnt] = j;
        cnt++;
      }
    }
  meta[0] = cnt;
}

// ---------------- K1: LITERAL gate-by-gate basis-column simulation ----------------
// One basis state per block; 256 threads hold the 256 amplitudes in LDS (fp32 complex).
// Applies every gate exactly as the reference does — no fusion anywhere.
__global__ __launch_bounds__(256) void build_u_kernel(const float* __restrict__ wt,
                                                      const float* __restrict__ coup,
                                                      void* __restrict__ wsv) {
  const int* meta = (const int*)wsv;
  float* Ut = (float*)((char*)wsv + 4096);
  const int c = blockIdx.x;
  const int tid = threadIdx.x;

  __shared__ float2 s[256];
  s[tid] = make_float2(tid == c ? 1.f : 0.f, 0.f);
  __syncthreads();

  // RZ: diagonal phase e^{-it/2} (bit=0) / e^{+it/2} (bit=1); own-element only
  auto RZg = [&](float t, int p) {
    float cz = cosf(0.5f * t), sz = sinf(0.5f * t);
    float2 a = s[tid];
    float2 r;
    if ((tid >> p) & 1) r = make_float2(cz * a.x - sz * a.y, cz * a.y + sz * a.x);
    else                r = make_float2(cz * a.x + sz * a.y, cz * a.y - sz * a.x);
    s[tid] = r;
    __syncthreads();
  };
  // RY = [[c,-s],[s,c]]
  auto RYg = [&](float t, int p) {
    float cy = cosf(0.5f * t), sy = sinf(0.5f * t);
    int m = 1 << p;
    float2 a0 = s[tid & ~m];
    float2 a1 = s[tid | m];
    __syncthreads();
    float2 r;
    if (tid & m) r = make_float2(sy * a0.x + cy * a1.x, sy * a0.y + cy * a1.y);
    else         r = make_float2(cy * a0.x - sy * a1.x, cy * a0.y - sy * a1.y);
    s[tid] = r;
    __syncthreads();
  };
  // RX = [[c,-is],[-is,c]]
  auto RXg = [&](float t, int p) {
    float cx = cosf(0.5f * t), sx = sinf(0.5f * t);
    int m = 1 << p;
    float2 a0 = s[tid & ~m];
    float2 a1 = s[tid | m];
    __syncthreads();
    float2 r;
    if (tid & m) r = make_float2(sx * a0.y + cx * a1.x, -sx * a0.x + cx * a1.y);
    else         r = make_float2(cx * a0.x + sx * a1.y, cx * a0.y - sx * a1.x);
    s[tid] = r;
    __syncthreads();
  };
  // CNOT control-bit pc, target-bit pt (gather form: src = CNOT(tid))
  auto CN = [&](int pc, int pt) {
    int src = ((tid >> pc) & 1) ? (tid ^ (1 << pt)) : tid;
    float2 v = s[src];
    __syncthreads();
    s[tid] = v;
    __syncthreads();
  };
  // SWAP bits p1,p2
  auto SW = [&](int p1, int p2) {
    int b1 = (tid >> p1) & 1, b2 = (tid >> p2) & 1;
    int src = (b1 != b2) ? (tid ^ (1 << p1) ^ (1 << p2)) : tid;
    float2 v = s[src];
    __syncthreads();
    s[tid] = v;
    __syncthreads();
  };

  // embedding rotations: per wire w (bit p = 7-w): RX, RY, RZ
  for (int w = 0; w < 8; w++) {
    int p = 7 - w;
    RXg(wt[w], p);
    RYg(wt[8 + w], p);
    RZg(wt[16 + w], p);
  }

  // IsingXX on all pairs: new = cos*own + (-i sin)*flip_both
  for (int i = 0; i < 8; i++)
    for (int j = i + 1; j < 8; j++) {
      float t = coup[i * 8 + j];
      float ch = cosf(0.5f * t), sn = sinf(0.5f * t);
      int mask = (1 << (7 - i)) | (1 << (7 - j));
      float2 a = s[tid];
      float2 b = s[tid ^ mask];
      __syncthreads();
      s[tid] = make_float2(ch * a.x + sn * b.y, ch * a.y - sn * b.x);
      __syncthreads();
    }

  // edges: [SWAP] conv pool [SWAP], every gate literal
  int ne = meta[0];
  for (int e = 0; e < ne; e++) {
    int i = meta[1 + 2 * e], jj = meta[2 + 2 * e];
    int pi = 7 - i, pj = 7 - jj;
    bool nonadj = (jj - i) != 1;
    const float* pw = wt + 24 + 6 * e;
    if (nonadj) SW(pi, pj);
    // conv
    RZg(-HP, pj);
    CN(pj, pi);
    RZg(pw[0], pi);
    RYg(pw[1], pj);
    CN(pi, pj);
    RYg(pw[2], pj);
    CN(pj, pi);
    RZg(HP, pi);
    // pool
    RZg(-HP, pj);
    CN(pj, pi);
    RZg(pw[3], pi);
    RYg(pw[4], pj);
    CN(pi, pj);
    RYg(pw[5], pj);
    if (nonadj) SW(pi, pj);
  }

  // write column c, transposed fp32: Ut[c][2r]=Re, Ut[c][2r+1]=Im
  Ut[c * 512 + 2 * tid]     = s[tid].x;
  Ut[c * 512 + 2 * tid + 1] = s[tid].y;
}

// ---------------- K2: dead-simple fp32 VALU GEMM + Z-reduce ----------------
// Block = 256 threads, 32 batch rows. Thread t owns state r=t and accumulates
// amp(re,im) for all 32 rows. U read from L2 (coalesced float2), psi via LDS broadcast.
__global__ __launch_bounds__(256) void gemm_simple(const float* __restrict__ x,
                                                   const void* __restrict__ wsv,
                                                   float* __restrict__ out) {
  const float* Ut = (const float*)((const char*)wsv + 4096);
  __shared__ float psi[32 * 256];   // 32 KB
  __shared__ float prob[256 * 32];  // 32 KB
  const int tid = threadIdx.x, blk = blockIdx.x;

  // stage + normalize 32 rows (8 threads/row)
  {
    const int rl = tid >> 3, seg = tid & 7;
    const float4* xs = (const float4*)(x + (size_t)(blk * 32 + rl) * 256 + seg * 32);
    float4 v[8];
    float ss = 0.f;
#pragma unroll
    for (int i2 = 0; i2 < 8; i2++) {
      v[i2] = xs[i2];
      ss += v[i2].x * v[i2].x + v[i2].y * v[i2].y + v[i2].z * v[i2].z + v[i2].w * v[i2].w;
    }
    ss += __shfl_xor(ss, 1);
    ss += __shfl_xor(ss, 2);
    ss += __shfl_xor(ss, 4);
    float inv = 1.0f / sqrtf(ss);
#pragma unroll
    for (int k = 0; k < 32; k++)
      psi[rl * 256 + seg * 32 + k] = ((const float*)v)[k] * inv;
  }
  __syncthreads();

  float are[32], aim[32];
#pragma unroll
  for (int b = 0; b < 32; b++) { are[b] = 0.f; aim[b] = 0.f; }

  for (int c = 0; c < 256; c += 4) {
    float2 uv0 = *(const float2*)&Ut[(size_t)(c + 0) * 512 + 2 * tid];
    float2 uv1 = *(const float2*)&Ut[(size_t)(c + 1) * 512 + 2 * tid];
    float2 uv2 = *(const float2*)&Ut[(size_t)(c + 2) * 512 + 2 * tid];
    float2 uv3 = *(const float2*)&Ut[(size_t)(c + 3) * 512 + 2 * tid];
#pragma unroll
    for (int b = 0; b < 32; b++) {
      float4 pv = *(const float4*)&psi[b * 256 + c];
      are[b] = fmaf(uv0.x, pv.x, are[b]);
      are[b] = fmaf(uv1.x, pv.y, are[b]);
      are[b] = fmaf(uv2.x, pv.z, are[b]);
      are[b] = fmaf(uv3.x, pv.w, are[b]);
      aim[b] = fmaf(uv0.y, pv.x, aim[b]);
      aim[b] = fmaf(uv1.y, pv.y, aim[b]);
      aim[b] = fmaf(uv2.y, pv.z, aim[b]);
      aim[b] = fmaf(uv3.y, pv.w, aim[b]);
    }
  }

#pragma unroll
  for (int b = 0; b < 32; b++)
    prob[tid * 32 + b] = are[b] * are[b] + aim[b] * aim[b];
  __syncthreads();

  // out[b][q] = sum_r (+-) prob[r][b], sign = bit(r, 7-q)
  {
    const int b = tid >> 3, q = tid & 7, sh = 7 - q;
    float acc = 0.f;
    for (int r = 0; r < 256; r++) {
      float p = prob[r * 32 + b];
      acc += ((r >> sh) & 1) ? -p : p;
    }
    out[(size_t)(blk * 32 + b) * 8 + q] = acc;
  }
}

extern "C" void kernel_launch(void* const* d_in, const int* in_sizes, int n_in,
                              void* d_out, int out_size, void* d_ws, size_t ws_size,
                              hipStream_t stream) {
  const float* x    = (const float*)d_in[0];
  const float* wt   = (const float*)d_in[1];
  const float* coup = (const float*)d_in[2];
  float* out = (float*)d_out;

  prep_kernel<<<1, 1, 0, stream>>>(coup, d_ws);
  build_u_kernel<<<256, 256, 0, stream>>>(wt, coup, d_ws);
  gemm_simple<<<2048, 256, 0, stream>>>(x, d_ws, out);
}